// Round 1
// baseline (16726.651 us; speedup 1.0000x reference)
//
#include <hip/hip_runtime.h>

#define Lnum 2
#define BSn  64
#define Tn   512
#define ECn  1024
#define CA1n 1024
#define NBLK 128

typedef short bf16x8 __attribute__((ext_vector_type(8)));
typedef float f32x4  __attribute__((ext_vector_type(4)));

#define MFMA16(a,b,c) __builtin_amdgcn_mfma_f32_16x16x32_bf16((a),(b),(c),0,0,0)

// d_out layout: [actCell 64*2][ec3his 2*512*1024][ec5his ...][ca1his ...]
#define OUT_E3  128
#define OUT_E5  (128 + Lnum*Tn*ECn)
#define OUT_CA1 (128 + 2*Lnum*Tn*ECn)

// ws layout (bytes)
#define WS_FLAGS 0
#define WS_EC3F  1024
#define WS_EC5F  (WS_EC3F + Lnum*BSn*ECn*4)
#define WS_EC3B  (WS_EC5F + Lnum*BSn*ECn*4)
#define WS_CA1B  (WS_EC3B + Lnum*BSn*ECn*2)
#define WS_CA1L  (WS_CA1B + Lnum*BSn*CA1n*2)
#define WS_S     (WS_CA1L + BSn*CA1n*4)
#define WS_BT3   (WS_S + Lnum*Tn*CA1n*4)

__device__ __forceinline__ float sigm(float x) { return 1.0f / (1.0f + __expf(-x)); }

__device__ __forceinline__ short f2bf(float f) {
  unsigned u = __float_as_uint(f);
  u += 0x7fffu + ((u >> 16) & 1u);   // RNE
  return (short)(u >> 16);
}

// ---------------- prep kernels ----------------

__global__ void prep_init(const float* __restrict__ ec3_last,
                          const float* __restrict__ ec5_last,
                          const float* __restrict__ inter_w,   // layer0 = first EC*CA1
                          unsigned* __restrict__ flags,
                          float* __restrict__ ec3f, float* __restrict__ ec5f,
                          short* __restrict__ ec3b, short* __restrict__ bt3g) {
  int idx = blockIdx.x * blockDim.x + threadIdx.x;
  int stride = gridDim.x * blockDim.x;
  if (idx < 256) flags[idx] = 0u;
  for (int i = idx; i < Lnum*BSn*ECn; i += stride) {
    float v = ec3_last[i];
    ec3f[i] = v; ec3b[i] = f2bf(v);
  }
  for (int i = idx; i < Lnum*BSn*ECn; i += stride) ec5f[i] = ec5_last[i];
  for (int i = idx; i < ECn*CA1n; i += stride) bt3g[i] = f2bf(inter_w[i]);
}

// S[(i*T + t)*CA1 + c] = sigmoid(10*(ca3_t . wca3ca1[i][:,c] - 0.5))
__global__ void prep_ca3(const float* __restrict__ wca3ca1, float* __restrict__ S) {
  const int t = blockIdx.x >> 1, i = blockIdx.x & 1;
  __shared__ float gauss[192];
  const float stepc = 512.0f / 1023.0f;
  const float tf = (float)t;
  int kmin = (int)floorf((tf - 40.0f) / stepc) - 1; if (kmin < 0) kmin = 0;
  int kmax = (int)ceilf((tf + 40.0f) / stepc) + 1;  if (kmax > 1023) kmax = 1023;
  int nw = kmax - kmin + 1;
  for (int j = threadIdx.x; j < nw; j += 256) {
    float d = (float)(kmin + j) * stepc - tf;
    gauss[j] = __expf(-d * d * 0.02f);   // 1/(2*sigma^2) = 0.02
  }
  __syncthreads();
  const float* W = wca3ca1 + i * (1024 * CA1n);
  for (int c = threadIdx.x; c < CA1n; c += 256) {
    float s = 0.0f;
    for (int j = 0; j < nw; ++j) s += gauss[j] * W[(kmin + j) * CA1n + c];
    S[(i * Tn + t) * CA1n + c] = sigm(10.0f * (s - 0.5f));
  }
}

// ---------------- barrier ----------------
__device__ __forceinline__ void gridbar(unsigned* flags, unsigned target) {
  __syncthreads();                    // drains each wave's vmcnt before s_barrier
  if (threadIdx.x == 0) {
    __threadfence();                  // agent release: write back L2
    __hip_atomic_store(&flags[blockIdx.x], target, __ATOMIC_RELAXED, __HIP_MEMORY_SCOPE_AGENT);
  }
  if (threadIdx.x < 64) {
    unsigned v0, v1;
    do {
      v0 = __hip_atomic_load(&flags[threadIdx.x],      __ATOMIC_RELAXED, __HIP_MEMORY_SCOPE_AGENT);
      v1 = __hip_atomic_load(&flags[threadIdx.x + 64], __ATOMIC_RELAXED, __HIP_MEMORY_SCOPE_AGENT);
    } while (__any((v0 < target) | (v1 < target)));
    if (threadIdx.x == 0) __threadfence();   // agent acquire: invalidate L1/L2
  }
  __syncthreads();
}

// ---------------- persistent RNN kernel ----------------
__global__ void __launch_bounds__(256, 1) rnn_persist(
    const float* __restrict__ cue,       // [64][512][1024]
    const float* __restrict__ wec3ca1,   // [2][1024][1024] (k,c)
    const float* __restrict__ wca1ec5,   // [2][1024][1024] (k,e)
    const float* __restrict__ ca1bias,   // [2][1024]
    const float* __restrict__ ec5bias,   // [2][1024]
    const float* __restrict__ interb,    // [2][1024], layer0 used
    const float* __restrict__ S,         // [2][512][1024]
    const short* __restrict__ bt3g,      // [1024][1024] bf16 (e,k)
    unsigned* __restrict__ flags,
    float* __restrict__ ec3f, float* __restrict__ ec5f,
    short* __restrict__ ec3b, short* __restrict__ ca1b,
    float* __restrict__ ca1l, float* __restrict__ out) {
  extern __shared__ short lds[];
  short* BT1 = lds;             // [16][1024] swizzled: idx = row*1024 + (k ^ ((row&7)<<3))
  short* BT2 = lds + 16 * 1024;
  short* BT3 = lds + 32 * 1024;

  const int b  = blockIdx.x;
  const int tid = threadIdx.x;
  const int i1 = b >> 6;             // phase-1 layer
  const int ct = b & 63;
  const int c0 = ct << 4;            // column tile start (16 cols)
  const int i2 = (b < 64) ? 0 : 1;   // phase-2 layer
  const bool hasG3 = (b >= 64);

  // ---- stage weight slices into LDS (one time) ----
  {
    const float* src1 = wec3ca1 + i1 * (ECn * CA1n) + c0;
    const float* src2 = wca1ec5 + i2 * (CA1n * ECn) + c0;
    int cp = tid & 15;
    int k0 = (tid >> 4) << 6;
    int xm = (cp & 7) << 3;
    for (int k = k0; k < k0 + 64; ++k) {
      BT1[cp * 1024 + (k ^ xm)] = f2bf(src1[k * CA1n + cp]);
      BT2[cp * 1024 + (k ^ xm)] = f2bf(src2[k * ECn + cp]);
    }
    if (hasG3) {
      int ep = tid >> 4;
      int kb0 = (tid & 15) << 6;
      int xm3 = (ep & 7) << 3;
      const short* src3 = bt3g + (c0 + ep) * CA1n;
      for (int k = kb0; k < kb0 + 64; ++k) BT3[ep * 1024 + (k ^ xm3)] = src3[k];
    }
  }
  __syncthreads();

  const int lane = tid & 63;
  const int wave = tid >> 6;
  const int fr = lane & 15;     // A-row-in-tile / B-col / C-col
  const int ks = lane >> 4;     // k-segment 0..3
  const int r0 = wave << 4;     // wave's 16-row group
  const int xsw = (fr & 7) << 3;

  const short* A1 = ec3b + i1 * (BSn * ECn) + (r0 + fr) * ECn + ks * 8;
  const short* A2 = ca1b + i2 * (BSn * CA1n) + (r0 + fr) * CA1n + ks * 8;
  const short* A3 = ca1b + (r0 + fr) * CA1n + ks * 8;      // layer-0 ca1
  const short* B1 = BT1 + fr * 1024;
  const short* B2 = BT2 + fr * 1024;
  const short* B3 = BT3 + fr * 1024;
  const int ccol = c0 + fr;

  unsigned tgt = 0;

  for (int t = 0; t < Tn; ++t) {
    // ---------- phase 1: ca1_i = relu(S * (1 + 3*sig(ec3@W)) - bias) ----------
    {
      f32x4 a0 = {0.f, 0.f, 0.f, 0.f}, a1 = {0.f, 0.f, 0.f, 0.f};
#pragma unroll
      for (int kk = 0; kk < 16; ++kk) {
        bf16x8 x0 = *(const bf16x8*)(A1 + kk * 32);
        bf16x8 w0 = *(const bf16x8*)(B1 + ((kk * 32 + ks * 8) ^ xsw));
        a0 = MFMA16(x0, w0, a0);
        bf16x8 x1 = *(const bf16x8*)(A1 + 512 + kk * 32);
        bf16x8 w1 = *(const bf16x8*)(B1 + ((512 + kk * 32 + ks * 8) ^ xsw));
        a1 = MFMA16(x1, w1, a1);
      }
      f32x4 acc = a0 + a1;
      float g = S[(i1 * Tn + t) * CA1n + ccol];
      float cb = ca1bias[i1 * CA1n + ccol];
#pragma unroll
      for (int r = 0; r < 4; ++r) {
        int grow = r0 + ks * 4 + r;
        float cv = fmaxf(g * (1.0f + 3.0f * sigm(acc[r])) - cb, 0.0f);
        ca1b[i1 * (BSn * CA1n) + grow * CA1n + ccol] = f2bf(cv);
        if (grow == 0) out[OUT_CA1 + (i1 * Tn + t) * CA1n + ccol] = cv;
        if (t == Tn - 1 && i1 == 1) ca1l[grow * CA1n + ccol] = cv;
      }
    }
    gridbar(flags, ++tgt);

    // ---------- phase 2: ec5/ec3 update ----------
    {
      f32x4 p0 = {0.f, 0.f, 0.f, 0.f}, p1 = {0.f, 0.f, 0.f, 0.f};
#pragma unroll
      for (int kk = 0; kk < 16; ++kk) {
        bf16x8 x0 = *(const bf16x8*)(A2 + kk * 32);
        bf16x8 w0 = *(const bf16x8*)(B2 + ((kk * 32 + ks * 8) ^ xsw));
        p0 = MFMA16(x0, w0, p0);
        bf16x8 x1 = *(const bf16x8*)(A2 + 512 + kk * 32);
        bf16x8 w1 = *(const bf16x8*)(B2 + ((512 + kk * 32 + ks * 8) ^ xsw));
        p1 = MFMA16(x1, w1, p1);
      }
      f32x4 g2 = p0 + p1;
      f32x4 g3 = {0.f, 0.f, 0.f, 0.f};
      if (hasG3) {
        f32x4 q0 = {0.f, 0.f, 0.f, 0.f}, q1 = {0.f, 0.f, 0.f, 0.f};
#pragma unroll
        for (int kk = 0; kk < 16; ++kk) {
          bf16x8 x0 = *(const bf16x8*)(A3 + kk * 32);
          bf16x8 w0 = *(const bf16x8*)(B3 + ((kk * 32 + ks * 8) ^ xsw));
          q0 = MFMA16(x0, w0, q0);
          bf16x8 x1 = *(const bf16x8*)(A3 + 512 + kk * 32);
          bf16x8 w1 = *(const bf16x8*)(B3 + ((512 + kk * 32 + ks * 8) ^ xsw));
          q1 = MFMA16(x1, w1, q1);
        }
        g3 = q0 + q1;
      }
      float e5b = ec5bias[i2 * ECn + ccol];
      float ib0 = interb[ccol];
#pragma unroll
      for (int r = 0; r < 4; ++r) {
        int grow = r0 + ks * 4 + r;
        int sidx = i2 * (BSn * ECn) + grow * ECn + ccol;
        float raw = ec5f[sidx] + g2[r] + e5b;          // 10*TS == 1.0f exactly
        float e5 = 0.69f + 0.3f * sigm(4.0f * (raw - 0.3f));
        ec5f[sidx] = e5;
        float xin = hasG3 ? (g3[r] + ib0) : cue[(grow * Tn + t) * ECn + ccol];
        float e3 = e5 * ec3f[sidx] + 0.6f * xin;
        ec3f[sidx] = e3;
        ec3b[sidx] = f2bf(e3);
        if (grow == 0) {
          out[OUT_E5 + (i2 * Tn + t) * ECn + ccol] = e5;
          out[OUT_E3 + (i2 * Tn + t) * ECn + ccol] = e3;
        }
      }
    }
    gridbar(flags, ++tgt);
  }
}

__global__ void act_cell(const float* __restrict__ ca1l, const float* __restrict__ wca1act,
                         const float* __restrict__ actbias, float* __restrict__ out) {
  int tid = threadIdx.x;
  if (tid < 128) {
    int b = tid >> 1, a = tid & 1;
    float s = 0.0f;
    for (int k = 0; k < 1024; ++k) s += ca1l[b * 1024 + k] * wca1act[k * 2 + a];
    out[b * 2 + a] = s + actbias[a];
  }
}

extern "C" void kernel_launch(void* const* d_in, const int* in_sizes, int n_in,
                              void* d_out, int out_size, void* d_ws, size_t ws_size,
                              hipStream_t stream) {
  (void)in_sizes; (void)n_in; (void)out_size; (void)ws_size;
  const float* cue      = (const float*)d_in[0];
  const float* ec3_last = (const float*)d_in[1];
  const float* ec5_last = (const float*)d_in[2];
  const float* wca3ca1  = (const float*)d_in[4];
  const float* wec3ca1  = (const float*)d_in[5];
  const float* wca1ec5  = (const float*)d_in[6];
  const float* ca1bias  = (const float*)d_in[7];
  const float* ec5bias  = (const float*)d_in[8];
  const float* inter_w  = (const float*)d_in[9];
  const float* inter_b  = (const float*)d_in[10];
  const float* wca1act  = (const float*)d_in[11];
  const float* actbias  = (const float*)d_in[12];
  float* out = (float*)d_out;

  char* ws = (char*)d_ws;
  unsigned* flags = (unsigned*)(ws + WS_FLAGS);
  float* ec3f = (float*)(ws + WS_EC3F);
  float* ec5f = (float*)(ws + WS_EC5F);
  short* ec3b = (short*)(ws + WS_EC3B);
  short* ca1b = (short*)(ws + WS_CA1B);
  float* ca1l = (float*)(ws + WS_CA1L);
  float* Stab = (float*)(ws + WS_S);
  short* bt3g = (short*)(ws + WS_BT3);

  prep_init<<<dim3(512), dim3(256), 0, stream>>>(ec3_last, ec5_last, inter_w,
                                                 flags, ec3f, ec5f, ec3b, bt3g);
  prep_ca3<<<dim3(1024), dim3(256), 0, stream>>>(wca3ca1, Stab);

  hipFuncSetAttribute((const void*)rnn_persist,
                      hipFuncAttributeMaxDynamicSharedMemorySize, 98304);

  void* args[] = {
      (void*)&cue, (void*)&wec3ca1, (void*)&wca1ec5, (void*)&ca1bias, (void*)&ec5bias,
      (void*)&inter_b, (void*)&Stab, (void*)&bt3g, (void*)&flags, (void*)&ec3f,
      (void*)&ec5f, (void*)&ec3b, (void*)&ca1b, (void*)&ca1l, (void*)&out};
  hipLaunchCooperativeKernel((void*)rnn_persist, dim3(NBLK), dim3(256), args,
                             98304, stream);

  act_cell<<<dim3(1), dim3(128), 0, stream>>>(ca1l, wca1act, actbias, out);
}

// Round 4
// 8320.044 us; speedup vs baseline: 2.0104x; 2.0104x over previous
//
#include <hip/hip_runtime.h>

#define Lnum 2
#define BSn  64
#define Tn   512
#define ECn  1024
#define CA1n 1024

typedef short bf16x8 __attribute__((ext_vector_type(8)));
typedef float f32x4  __attribute__((ext_vector_type(4)));

#define MFMA16(a,b,c) __builtin_amdgcn_mfma_f32_16x16x32_bf16((a),(b),(c),0,0,0)

// d_out layout: [actCell 64*2][ec3his 2*512*1024][ec5his ...][ca1his ...]
#define OUT_E3  128
#define OUT_E5  (128 + Lnum*Tn*ECn)
#define OUT_CA1 (128 + 2*Lnum*Tn*ECn)

// ws layout (bytes)
#define WS_EC3B 0                       // bf16 [2][64][1024]
#define WS_CA1B 262144                  // bf16 [2][64][1024]
#define WS_EC5F 524288                  // f32  [2][64][1024]
#define WS_EC3F 1048576                 // f32  [2][64][1024]
#define WS_CA1L 1572864                 // f32  [64][1024]
#define WS_S    1835008                 // bf16 [2][512][1024]
#define WS_W1T  3932160                 // bf16 [2][1024c][1024k]
#define WS_W2T  8126464                 // bf16 [2][1024e][1024k]
#define WS_W3T  12320768                // bf16 [1024e][1024k]

__device__ __forceinline__ float sigm(float x) { return 1.0f / (1.0f + __expf(-x)); }

__device__ __forceinline__ short f2bf(float f) {
  unsigned u = __float_as_uint(f);
  u += 0x7fffu + ((u >> 16) & 1u);   // RNE
  return (short)(u >> 16);
}
__device__ __forceinline__ float bf2f(short s) {
  return __uint_as_float(((unsigned)(unsigned short)s) << 16);
}

// ---------------- prep kernels ----------------

__global__ void prep_state(const float* __restrict__ ec3_last,
                           const float* __restrict__ ec5_last,
                           short* __restrict__ ec3b,
                           float* __restrict__ ec5f, float* __restrict__ ec3f) {
  int i = blockIdx.x * blockDim.x + threadIdx.x;   // 512*256 = 131072 = exactly L*BS*EC
  float v3 = ec3_last[i];
  ec3b[i] = f2bf(v3);
  ec3f[i] = v3;
  ec5f[i] = ec5_last[i];
}

// 64x64 LDS tile transpose fp32[k][c] -> bf16[c][k], for W1 (m=0) and W2 (m=1)
__global__ void prep_wt(const float* __restrict__ w1, const float* __restrict__ w2,
                        short* __restrict__ w1t, short* __restrict__ w2t) {
  __shared__ float tile[64][65];
  const int b = blockIdx.x;               // 1024 = 2 mats * 2 layers * 16*16 tiles
  const int m  = b >> 9;
  const int li = (b >> 8) & 1;
  const int kt = (b >> 4) & 15;
  const int ct = b & 15;
  const float* src = (m == 0 ? w1 : w2) + li * (1024 * 1024);
  short* dst = (m == 0 ? w1t : w2t) + li * (1024 * 1024);
#pragma unroll
  for (int i = 0; i < 16; ++i) {
    int idx = threadIdx.x + i * 256;
    int r = idx >> 6, c = idx & 63;
    tile[r][c] = src[(kt * 64 + r) * 1024 + ct * 64 + c];
  }
  __syncthreads();
#pragma unroll
  for (int i = 0; i < 16; ++i) {
    int idx = threadIdx.x + i * 256;
    int c = idx >> 6, r = idx & 63;
    dst[(ct * 64 + c) * 1024 + kt * 64 + r] = f2bf(tile[r][c]);
  }
}

__global__ void prep_w3(const float* __restrict__ inter_w, short* __restrict__ w3t) {
  int i = blockIdx.x * blockDim.x + threadIdx.x;   // 4096*256 = 1048576
  w3t[i] = f2bf(inter_w[i]);                        // layer 0 slice, already [e][k]
}

// S[(li*T+t)*1024+c] = bf16(sigmoid(10*(ca3_t . wca3ca1[li][:,c] - 0.5)))
__global__ void prep_ca3(const float* __restrict__ wca3ca1, short* __restrict__ S) {
  const int t = blockIdx.x >> 1, li = blockIdx.x & 1;
  __shared__ float gauss[192];
  const float stepc = 512.0f / 1023.0f;
  const float tf = (float)t;
  int kmin = (int)floorf((tf - 40.0f) / stepc) - 1; if (kmin < 0) kmin = 0;
  int kmax = (int)ceilf((tf + 40.0f) / stepc) + 1;  if (kmax > 1023) kmax = 1023;
  int nw = kmax - kmin + 1;
  for (int j = threadIdx.x; j < nw; j += 256) {
    float d = (float)(kmin + j) * stepc - tf;
    gauss[j] = __expf(-d * d * 0.02f);
  }
  __syncthreads();
  const float* W = wca3ca1 + li * (1024 * 1024);
  for (int c = threadIdx.x; c < 1024; c += 256) {
    float s = 0.0f;
    for (int j = 0; j < nw; ++j) s += gauss[j] * W[(kmin + j) * 1024 + c];
    S[(li * Tn + t) * 1024 + c] = f2bf(sigm(10.0f * (s - 0.5f)));
  }
}

// ---------------- per-step phase kernels ----------------
// grid 256 = [mh:1][li:1][ctile:6], block 128 (2 waves). No LDS.

__global__ void __launch_bounds__(128) phaseA(
    const short* __restrict__ ec3b, const short* __restrict__ w1t,
    const short* __restrict__ stab, const float* __restrict__ ca1bias,
    short* __restrict__ ca1b, float* __restrict__ ca1l,
    float* __restrict__ out, int t) {
  const int b = blockIdx.x;
  const int mh = b >> 7, li = (b >> 6) & 1, c0 = (b & 63) << 4;
  const int tid = threadIdx.x;
  const int lane = tid & 63, wave = tid >> 6;
  const int fr = lane & 15, ks = lane >> 4;
  const int r0 = (mh * 2 + wave) << 4;
  const short* A = ec3b + li * 65536 + (r0 + fr) * 1024 + ks * 8;
  const short* B = w1t + li * 1048576 + (c0 + fr) * 1024 + ks * 8;
  f32x4 a0 = {0.f,0.f,0.f,0.f}, a1 = {0.f,0.f,0.f,0.f};
#pragma unroll
  for (int kk = 0; kk < 16; ++kk) {
    a0 = MFMA16(*(const bf16x8*)(A + kk * 32),       *(const bf16x8*)(B + kk * 32),       a0);
    a1 = MFMA16(*(const bf16x8*)(A + 512 + kk * 32), *(const bf16x8*)(B + 512 + kk * 32), a1);
  }
  f32x4 acc = a0 + a1;
  const int ccol = c0 + fr;
  const float g  = bf2f(stab[(li * Tn + t) * 1024 + ccol]);
  const float cb = ca1bias[li * 1024 + ccol];
#pragma unroll
  for (int r = 0; r < 4; ++r) {
    int grow = r0 + ks * 4 + r;
    float cv = fmaxf(g * (1.0f + 3.0f * sigm(acc[r])) - cb, 0.0f);
    ca1b[li * 65536 + grow * 1024 + ccol] = f2bf(cv);
    if (grow == 0) out[OUT_CA1 + (li * Tn + t) * 1024 + ccol] = cv;
    if (t == Tn - 1 && li == 1) ca1l[grow * 1024 + ccol] = cv;
  }
}

__global__ void __launch_bounds__(128) phaseB(
    const short* __restrict__ ca1b, const short* __restrict__ w2t,
    const short* __restrict__ w3t, const float* __restrict__ cue,
    const float* __restrict__ ec5bias, const float* __restrict__ interb,
    float* __restrict__ ec5f, float* __restrict__ ec3f,
    short* __restrict__ ec3b, float* __restrict__ out, int t) {
  const int b = blockIdx.x;
  const int mh = b >> 7, li = (b >> 6) & 1, e0 = (b & 63) << 4;
  const int tid = threadIdx.x;
  const int lane = tid & 63, wave = tid >> 6;
  const int fr = lane & 15, ks = lane >> 4;
  const int r0 = (mh * 2 + wave) << 4;
  const short* A2 = ca1b + li * 65536 + (r0 + fr) * 1024 + ks * 8;
  const short* B2 = w2t + li * 1048576 + (e0 + fr) * 1024 + ks * 8;
  const int ecol = e0 + fr;

  f32x4 p0 = {0.f,0.f,0.f,0.f}, p1 = {0.f,0.f,0.f,0.f};
#pragma unroll
  for (int kk = 0; kk < 16; ++kk) {
    p0 = MFMA16(*(const bf16x8*)(A2 + kk * 32),       *(const bf16x8*)(B2 + kk * 32),       p0);
    p1 = MFMA16(*(const bf16x8*)(A2 + 512 + kk * 32), *(const bf16x8*)(B2 + 512 + kk * 32), p1);
  }
  f32x4 g2 = p0 + p1;

  f32x4 xin;
  if (li == 1) {
    const short* A3 = ca1b + (r0 + fr) * 1024 + ks * 8;       // layer-0 ca1
    const short* B3 = w3t + (e0 + fr) * 1024 + ks * 8;
    f32x4 q0 = {0.f,0.f,0.f,0.f}, q1 = {0.f,0.f,0.f,0.f};
#pragma unroll
    for (int kk = 0; kk < 16; ++kk) {
      q0 = MFMA16(*(const bf16x8*)(A3 + kk * 32),       *(const bf16x8*)(B3 + kk * 32),       q0);
      q1 = MFMA16(*(const bf16x8*)(A3 + 512 + kk * 32), *(const bf16x8*)(B3 + 512 + kk * 32), q1);
    }
    f32x4 q = q0 + q1;
    float ib = interb[ecol];
#pragma unroll
    for (int r = 0; r < 4; ++r) xin[r] = q[r] + ib;
  } else {
#pragma unroll
    for (int r = 0; r < 4; ++r)
      xin[r] = cue[((r0 + ks * 4 + r) * Tn + t) * 1024 + ecol];
  }

  const float e5b = ec5bias[li * 1024 + ecol];
#pragma unroll
  for (int r = 0; r < 4; ++r) {
    int grow = r0 + ks * 4 + r;
    int sidx = li * 65536 + grow * 1024 + ecol;
    float raw = ec5f[sidx] + g2[r] + e5b;            // 10*TS == 1.0f exactly
    float e5 = 0.69f + 0.3f * sigm(4.0f * (raw - 0.3f));
    ec5f[sidx] = e5;
    float e3 = e5 * ec3f[sidx] + 0.6f * xin[r];
    ec3f[sidx] = e3;
    ec3b[sidx] = f2bf(e3);
    if (grow == 0) {
      out[OUT_E5 + (li * Tn + t) * 1024 + ecol] = e5;
      out[OUT_E3 + (li * Tn + t) * 1024 + ecol] = e3;
    }
  }
}

__global__ void act_cell(const float* __restrict__ ca1l, const float* __restrict__ wca1act,
                         const float* __restrict__ actbias, float* __restrict__ out) {
  int tid = threadIdx.x;
  if (tid < 128) {
    int b = tid >> 1, a = tid & 1;
    float s = 0.0f;
    for (int k = 0; k < 1024; ++k) s += ca1l[b * 1024 + k] * wca1act[k * 2 + a];
    out[b * 2 + a] = s + actbias[a];
  }
}

extern "C" void kernel_launch(void* const* d_in, const int* in_sizes, int n_in,
                              void* d_out, int out_size, void* d_ws, size_t ws_size,
                              hipStream_t stream) {
  (void)in_sizes; (void)n_in; (void)out_size; (void)ws_size;
  const float* cue      = (const float*)d_in[0];
  const float* ec3_last = (const float*)d_in[1];
  const float* ec5_last = (const float*)d_in[2];
  const float* wca3ca1  = (const float*)d_in[4];
  const float* wec3ca1  = (const float*)d_in[5];
  const float* wca1ec5  = (const float*)d_in[6];
  const float* ca1bias  = (const float*)d_in[7];
  const float* ec5bias  = (const float*)d_in[8];
  const float* inter_w  = (const float*)d_in[9];
  const float* inter_b  = (const float*)d_in[10];
  const float* wca1act  = (const float*)d_in[11];
  const float* actbias  = (const float*)d_in[12];
  float* out = (float*)d_out;

  char* ws = (char*)d_ws;
  short* ec3b = (short*)(ws + WS_EC3B);
  short* ca1b = (short*)(ws + WS_CA1B);
  float* ec5f = (float*)(ws + WS_EC5F);
  float* ec3f = (float*)(ws + WS_EC3F);
  float* ca1l = (float*)(ws + WS_CA1L);
  short* stab = (short*)(ws + WS_S);
  short* w1t  = (short*)(ws + WS_W1T);
  short* w2t  = (short*)(ws + WS_W2T);
  short* w3t  = (short*)(ws + WS_W3T);

  prep_state<<<dim3(512), dim3(256), 0, stream>>>(ec3_last, ec5_last, ec3b, ec5f, ec3f);
  prep_wt<<<dim3(1024), dim3(256), 0, stream>>>(wec3ca1, wca1ec5, w1t, w2t);
  prep_w3<<<dim3(4096), dim3(256), 0, stream>>>(inter_w, w3t);
  prep_ca3<<<dim3(1024), dim3(256), 0, stream>>>(wca3ca1, stab);

  for (int t = 0; t < Tn; ++t) {
    phaseA<<<dim3(256), dim3(128), 0, stream>>>(ec3b, w1t, stab, ca1bias, ca1b, ca1l, out, t);
    phaseB<<<dim3(256), dim3(128), 0, stream>>>(ca1b, w2t, w3t, cue, ec5bias, inter_b,
                                                ec5f, ec3f, ec3b, out, t);
  }

  act_cell<<<dim3(1), dim3(128), 0, stream>>>(ca1l, wca1act, actbias, out);
}